// Round 9
// baseline (366.386 us; speedup 1.0000x reference)
//
#include <hip/hip_runtime.h>
#include <stdint.h>

// Round 9: (a) FFN2 re-tiled 128x128 split-K=4 (grid still 1024 = 4/CU,
// id%8==p%8 XCD locality): staging 786->512 MB (n64 tile was 1.5KB/MFMA vs
// 1.0 for n128), atomics 32->64 MB into b2-pre-initialized d_out.
// (b) gemm_s gets XCD locality: 2048-slot launch, i64=id&63 (co-XCD for
// Q-tile sharers), bn=id>>6, early-exit on 992 invalid slots.
// Everything else unchanged from R8. BK=64, XOR LDS swizzle, shift-free
// softmax, operand-swapped-V QKV. ws: 159 MB.

using short8 = __attribute__((ext_vector_type(8))) short;
using f32x4  = __attribute__((ext_vector_type(4))) float;

__device__ __forceinline__ uint16_t f2bf(float f) {
  uint32_t u = __builtin_bit_cast(uint32_t, f);
  u += 0x7FFFu + ((u >> 16) & 1u);        // RNE, inputs are finite
  return (uint16_t)(u >> 16);
}

__device__ __forceinline__ void gload_lds16(const uint16_t* g, uint16_t* l) {
  __builtin_amdgcn_global_load_lds(
      (__attribute__((address_space(1))) void*)(void*)g,
      (__attribute__((address_space(3))) void*)l, 16, 0, 0);
}

// LDS swizzle (BK=64): 16B slot s holds global chunk-col (s&7)^((s>>3)&7) of
// row s>>3. Read (row r, chunk cc) -> slot r*8 + (cc ^ (r&7)).

// ---------------- QKV gemm: 128x128, 1-D grid 768 (id%8==bm%8) --------------
// bn<16: C[m][n] -> QKVb (bias fused, bf16). bn>=16 (V): operand-swapped
// MFMA gives D[n][m]; store straight to Vt[n][m] (32B-contiguous in m).
__global__ __launch_bounds__(256) void gemm_qkv(
    const uint16_t* __restrict__ A, const uint16_t* __restrict__ Bt,
    const float* __restrict__ bias, uint16_t* __restrict__ Cout,
    uint16_t* __restrict__ Vt)
{
  constexpr int BK = 64;
  __shared__ uint16_t As[128 * BK];
  __shared__ uint16_t Bs[128 * BK];
  int id = blockIdx.x;
  int bm = id & 31, bn = id >> 5;
  bool vblk = (bn >= 16);

  int tid  = threadIdx.x;
  int lane = tid & 63;
  int wave = tid >> 6;
  int wm = (wave >> 1) * 64, wn = (wave & 1) * 64;
  int lr = lane & 15, quad = lane >> 4;

  const uint16_t *Ag[4], *Bg[4];
  uint16_t *Al[4], *Bl[4];
#pragma unroll
  for (int s = 0; s < 4; ++s) {
    int c = tid + 256 * s;
    int r = c >> 3, q = (c & 7) ^ (r & 7);
    Ag[s] = A  + (size_t)(bm * 128 + r) * 1024 + q * 8;
    Bg[s] = Bt + (size_t)(bn * 128 + r) * 1024 + q * 8;
    Al[s] = As + c * 8;
    Bl[s] = Bs + c * 8;
  }
  const uint16_t* Fa = vblk ? Bs : As;
  const uint16_t* Fb = vblk ? As : Bs;

  f32x4 acc[4][4] = {};

  for (int k0 = 0; k0 < 1024; k0 += BK) {
    __syncthreads();
#pragma unroll
    for (int s = 0; s < 4; ++s) gload_lds16(Ag[s] + k0, Al[s]);
#pragma unroll
    for (int s = 0; s < 4; ++s) gload_lds16(Bg[s] + k0, Bl[s]);
    __syncthreads();
#pragma unroll
    for (int h = 0; h < 2; ++h) {
      short8 af[4], bfr[4];
      int cc = quad + 4 * h;
#pragma unroll
      for (int i = 0; i < 4; ++i) {
        int r = wm + i * 16 + lr;
        af[i] = *(const short8*)(&Fa[(r * 8 + (cc ^ (r & 7))) * 8]);
      }
#pragma unroll
      for (int j = 0; j < 4; ++j) {
        int r = wn + j * 16 + lr;
        bfr[j] = *(const short8*)(&Fb[(r * 8 + (cc ^ (r & 7))) * 8]);
      }
#pragma unroll
      for (int i = 0; i < 4; ++i)
#pragma unroll
        for (int j = 0; j < 4; ++j)
          acc[i][j] = __builtin_amdgcn_mfma_f32_16x16x32_bf16(af[i], bfr[j], acc[i][j], 0, 0, 0);
    }
  }

  if (vblk) {
#pragma unroll
    for (int i = 0; i < 4; ++i) {
#pragma unroll
      for (int r = 0; r < 4; ++r) {
        int n = bn * 128 + wm + i * 16 + quad * 4 + r;
        float bv = bias[n];
        uint16_t* dst = Vt + (size_t)(n - 2048) * 4096 + bm * 128;
#pragma unroll
        for (int j = 0; j < 4; ++j)
          dst[wn + j * 16 + lr] = f2bf(acc[i][j][r] + bv);
      }
    }
  } else {
    int row0 = bm * 128 + wm + quad * 4;
    int col0 = bn * 128 + wn + lr;
#pragma unroll
    for (int j = 0; j < 4; ++j) {
      int col = col0 + j * 16;
      float bv = bias[col];
#pragma unroll
      for (int i = 0; i < 4; ++i)
#pragma unroll
        for (int r = 0; r < 4; ++r)
          Cout[(size_t)(row0 + i * 16 + r) * 3072 + col] = f2bf(acc[i][j][r] + bv);
    }
  }
}

// ---------------- FFN1 gemm: 128x128, 1-D grid 1024 (id%8==bm%8) ------------
__global__ __launch_bounds__(256) void gemm_ffn1(
    const uint16_t* __restrict__ A, const uint16_t* __restrict__ Bt,
    const float* __restrict__ bias, uint16_t* __restrict__ Cout)
{
  constexpr int BK = 64;
  __shared__ uint16_t As[128 * BK];
  __shared__ uint16_t Bs[128 * BK];
  int id = blockIdx.x;
  int bm = id & 31, bn = id >> 5;

  int tid  = threadIdx.x;
  int lane = tid & 63;
  int wave = tid >> 6;
  int wm = (wave >> 1) * 64, wn = (wave & 1) * 64;
  int lr = lane & 15, quad = lane >> 4;

  const uint16_t *Ag[4], *Bg[4];
  uint16_t *Al[4], *Bl[4];
#pragma unroll
  for (int s = 0; s < 4; ++s) {
    int c = tid + 256 * s;
    int r = c >> 3, q = (c & 7) ^ (r & 7);
    Ag[s] = A  + (size_t)(bm * 128 + r) * 1024 + q * 8;
    Bg[s] = Bt + (size_t)(bn * 128 + r) * 1024 + q * 8;
    Al[s] = As + c * 8;
    Bl[s] = Bs + c * 8;
  }

  f32x4 acc[4][4] = {};

  for (int k0 = 0; k0 < 1024; k0 += BK) {
    __syncthreads();
#pragma unroll
    for (int s = 0; s < 4; ++s) gload_lds16(Ag[s] + k0, Al[s]);
#pragma unroll
    for (int s = 0; s < 4; ++s) gload_lds16(Bg[s] + k0, Bl[s]);
    __syncthreads();
#pragma unroll
    for (int h = 0; h < 2; ++h) {
      short8 af[4], bfr[4];
      int cc = quad + 4 * h;
#pragma unroll
      for (int i = 0; i < 4; ++i) {
        int r = wm + i * 16 + lr;
        af[i] = *(const short8*)(&As[(r * 8 + (cc ^ (r & 7))) * 8]);
      }
#pragma unroll
      for (int j = 0; j < 4; ++j) {
        int r = wn + j * 16 + lr;
        bfr[j] = *(const short8*)(&Bs[(r * 8 + (cc ^ (r & 7))) * 8]);
      }
#pragma unroll
      for (int i = 0; i < 4; ++i)
#pragma unroll
        for (int j = 0; j < 4; ++j)
          acc[i][j] = __builtin_amdgcn_mfma_f32_16x16x32_bf16(af[i], bfr[j], acc[i][j], 0, 0, 0);
    }
  }

  int row0 = bm * 128 + wm + quad * 4;
  int col0 = bn * 128 + wn + lr;
#pragma unroll
  for (int j = 0; j < 4; ++j) {
    int col = col0 + j * 16;
    float bv = bias[col];
#pragma unroll
    for (int i = 0; i < 4; ++i)
#pragma unroll
      for (int r = 0; r < 4; ++r)
        Cout[(size_t)(row0 + i * 16 + r) * 4096 + col] =
            f2bf(fmaxf(acc[i][j][r] + bv, 0.0f));
  }
}

// ---------------- causal S-gemm, 64x128 tiles, XCD-swizzled -----------------
// 1-D grid 2048: i64 = id&63 (64%8==0 -> Q-tile sharers co-XCD), bn = id>>6;
// early-exit if bn > i64>>1 (992 empty slots). Fused row-sum atomics.
__global__ __launch_bounds__(256) void gemm_s(
    const uint16_t* __restrict__ Qm, const uint16_t* __restrict__ Km,
    uint16_t* __restrict__ Sb, float* __restrict__ lvec,
    int lda, int ldb, int ldc, float scale)
{
  constexpr int BK = 64;
  __shared__ uint16_t As[64 * BK];
  __shared__ uint16_t Bs[128 * BK];
  int id = blockIdx.x;
  int i64 = id & 63, bn = id >> 6;
  if (bn > (i64 >> 1)) return;

  int tid  = threadIdx.x;
  int lane = tid & 63;
  int wave = tid >> 6;
  int wm = (wave >> 1) * 32, wn = (wave & 1) * 64;
  int lr = lane & 15, quad = lane >> 4;

  const uint16_t *Ag[2], *Bg[4];
  uint16_t *Al[2], *Bl[4];
#pragma unroll
  for (int s = 0; s < 2; ++s) {
    int c = tid + 256 * s;
    int r = c >> 3, q = (c & 7) ^ (r & 7);
    Ag[s] = Qm + (size_t)(i64 * 64 + r) * lda + q * 8;
    Al[s] = As + c * 8;
  }
#pragma unroll
  for (int s = 0; s < 4; ++s) {
    int c = tid + 256 * s;
    int r = c >> 3, q = (c & 7) ^ (r & 7);
    Bg[s] = Km + (size_t)(bn * 128 + r) * ldb + q * 8;
    Bl[s] = Bs + c * 8;
  }

  f32x4 acc[2][4] = {};

  for (int k0 = 0; k0 < 1024; k0 += BK) {
    __syncthreads();
#pragma unroll
    for (int s = 0; s < 2; ++s) gload_lds16(Ag[s] + k0, Al[s]);
#pragma unroll
    for (int s = 0; s < 4; ++s) gload_lds16(Bg[s] + k0, Bl[s]);
    __syncthreads();
#pragma unroll
    for (int h = 0; h < 2; ++h) {
      short8 af[2], bfr[4];
      int cc = quad + 4 * h;
#pragma unroll
      for (int i = 0; i < 2; ++i) {
        int r = wm + i * 16 + lr;
        af[i] = *(const short8*)(&As[(r * 8 + (cc ^ (r & 7))) * 8]);
      }
#pragma unroll
      for (int j = 0; j < 4; ++j) {
        int r = wn + j * 16 + lr;
        bfr[j] = *(const short8*)(&Bs[(r * 8 + (cc ^ (r & 7))) * 8]);
      }
#pragma unroll
      for (int i = 0; i < 2; ++i)
#pragma unroll
        for (int j = 0; j < 4; ++j)
          acc[i][j] = __builtin_amdgcn_mfma_f32_16x16x32_bf16(af[i], bfr[j], acc[i][j], 0, 0, 0);
    }
  }

  int row0 = i64 * 64 + wm + quad * 4;
  int col0 = bn * 128 + wn + lr;
#pragma unroll
  for (int i = 0; i < 2; ++i) {
#pragma unroll
    for (int r = 0; r < 4; ++r) {
      int row = row0 + i * 16 + r;
      float s = 0.0f;
#pragma unroll
      for (int j = 0; j < 4; ++j) {
        int col = col0 + j * 16;
        float v = (col <= row) ? __expf(acc[i][j][r] * scale) : 0.0f;
        Sb[(size_t)row * ldc + col] = f2bf(v);
        s += v;
      }
#pragma unroll
      for (int o = 8; o > 0; o >>= 1) s += __shfl_xor(s, o, 64);
      if (lr == 0) unsafeAtomicAdd(&lvec[row], s);
    }
  }
}

// ---------------- O-gemm: 128x128, triangular K-chunks, XCD-swizzled --------
__global__ __launch_bounds__(256) void gemm_o(
    const uint16_t* __restrict__ Sb, const uint16_t* __restrict__ Vt,
    float* __restrict__ Opart)
{
  constexpr int BK = 64;
  __shared__ uint16_t As[128 * BK];
  __shared__ uint16_t Bs[128 * BK];
  int id = blockIdx.x;
  int bn = id / 80, p = id % 80;
  int c, bm;
  if      (p < 32) { c = 0; bm = p; }
  else if (p < 56) { c = 1; bm = p - 24; }
  else if (p < 72) { c = 2; bm = p - 40; }
  else             { c = 3; bm = p - 48; }
  int klo = c << 10;
  int khi = (bm + 1) << 7; if (khi > ((c + 1) << 10)) khi = (c + 1) << 10;

  int tid  = threadIdx.x;
  int lane = tid & 63;
  int wave = tid >> 6;
  int wm = (wave >> 1) * 64, wn = (wave & 1) * 64;
  int lr = lane & 15, quad = lane >> 4;

  const uint16_t *Ag[4], *Bg[4];
  uint16_t *Al[4], *Bl[4];
#pragma unroll
  for (int s = 0; s < 4; ++s) {
    int cch = tid + 256 * s;
    int r = cch >> 3, q = (cch & 7) ^ (r & 7);
    Ag[s] = Sb + (size_t)(bm * 128 + r) * 4096 + q * 8;
    Bg[s] = Vt + (size_t)(bn * 128 + r) * 4096 + q * 8;
    Al[s] = As + cch * 8;
    Bl[s] = Bs + cch * 8;
  }

  f32x4 acc[4][4] = {};

  for (int k0 = klo; k0 < khi; k0 += BK) {
    __syncthreads();
#pragma unroll
    for (int s = 0; s < 4; ++s) gload_lds16(Ag[s] + k0, Al[s]);
#pragma unroll
    for (int s = 0; s < 4; ++s) gload_lds16(Bg[s] + k0, Bl[s]);
    __syncthreads();
#pragma unroll
    for (int h = 0; h < 2; ++h) {
      short8 af[4], bfr[4];
      int cc = quad + 4 * h;
#pragma unroll
      for (int i = 0; i < 4; ++i) {
        int r = wm + i * 16 + lr;
        af[i] = *(const short8*)(&As[(r * 8 + (cc ^ (r & 7))) * 8]);
      }
#pragma unroll
      for (int j = 0; j < 4; ++j) {
        int r = wn + j * 16 + lr;
        bfr[j] = *(const short8*)(&Bs[(r * 8 + (cc ^ (r & 7))) * 8]);
      }
#pragma unroll
      for (int i = 0; i < 4; ++i)
#pragma unroll
        for (int j = 0; j < 4; ++j)
          acc[i][j] = __builtin_amdgcn_mfma_f32_16x16x32_bf16(af[i], bfr[j], acc[i][j], 0, 0, 0);
    }
  }

  float* P = Opart + (size_t)c * 4194304;
  int row0 = bm * 128 + wm + quad * 4;
  int col0 = bn * 128 + wn + lr;
#pragma unroll
  for (int j = 0; j < 4; ++j)
#pragma unroll
    for (int i = 0; i < 4; ++i)
#pragma unroll
      for (int r = 0; r < 4; ++r)
        P[(size_t)(row0 + i * 16 + r) * 1024 + col0 + j * 16] = acc[i][j][r];
}

// ---------------- FFN2: 128x128, split-K=4, atomic epilogue, XCD-swizzled ---
// 1-D grid 1024: id = bn*128 + p (128%8==0 -> id%8==p%8, A-chunk co-XCD).
// p -> bm = p>>2, kq = p&3; K range [kq*1024, (kq+1)*1024).
// unsafeAtomicAdd into fp32 Cout (pre-initialized with b2 by prep).
__global__ __launch_bounds__(256) void gemm_ffn2(
    const uint16_t* __restrict__ A, const uint16_t* __restrict__ Bt,
    float* __restrict__ Cout)
{
  constexpr int BK = 64;
  __shared__ uint16_t As[128 * BK];
  __shared__ uint16_t Bs[128 * BK];
  int id = blockIdx.x;
  int bn = id >> 7, p = id & 127;
  int bm = p >> 2, kq = p & 3;
  int klo = kq << 10, khi = klo + 1024;

  int tid  = threadIdx.x;
  int lane = tid & 63;
  int wave = tid >> 6;
  int wm = (wave >> 1) * 64, wn = (wave & 1) * 64;
  int lr = lane & 15, quad = lane >> 4;

  const uint16_t *Ag[4], *Bg[4];
  uint16_t *Al[4], *Bl[4];
#pragma unroll
  for (int s = 0; s < 4; ++s) {
    int c = tid + 256 * s;
    int r = c >> 3, q = (c & 7) ^ (r & 7);
    Ag[s] = A  + (size_t)(bm * 128 + r) * 4096 + q * 8;
    Bg[s] = Bt + (size_t)(bn * 128 + r) * 4096 + q * 8;
    Al[s] = As + c * 8;
    Bl[s] = Bs + c * 8;
  }

  f32x4 acc[4][4] = {};

  for (int k0 = klo; k0 < khi; k0 += BK) {
    __syncthreads();
#pragma unroll
    for (int s = 0; s < 4; ++s) gload_lds16(Ag[s] + k0, Al[s]);
#pragma unroll
    for (int s = 0; s < 4; ++s) gload_lds16(Bg[s] + k0, Bl[s]);
    __syncthreads();
#pragma unroll
    for (int h = 0; h < 2; ++h) {
      short8 af[4], bfr[4];
      int cc = quad + 4 * h;
#pragma unroll
      for (int i = 0; i < 4; ++i) {
        int r = wm + i * 16 + lr;
        af[i] = *(const short8*)(&As[(r * 8 + (cc ^ (r & 7))) * 8]);
      }
#pragma unroll
      for (int j = 0; j < 4; ++j) {
        int r = wn + j * 16 + lr;
        bfr[j] = *(const short8*)(&Bs[(r * 8 + (cc ^ (r & 7))) * 8]);
      }
#pragma unroll
      for (int i = 0; i < 4; ++i)
#pragma unroll
        for (int j = 0; j < 4; ++j)
          acc[i][j] = __builtin_amdgcn_mfma_f32_16x16x32_bf16(af[i], bfr[j], acc[i][j], 0, 0, 0);
    }
  }

  int row0 = bm * 128 + wm + quad * 4;
  int col0 = bn * 128 + wn + lr;
#pragma unroll
  for (int j = 0; j < 4; ++j)
#pragma unroll
    for (int i = 0; i < 4; ++i)
#pragma unroll
      for (int r = 0; r < 4; ++r) {
        size_t idx = (size_t)(row0 + i * 16 + r) * 1024 + col0 + j * 16;
        unsafeAtomicAdd(&Cout[idx], acc[i][j][r]);
      }
}

// ---------------- reductions ------------------------------------------------
__device__ __forceinline__ float block_sum(float v, float* red) {
#pragma unroll
  for (int o = 32; o > 0; o >>= 1) v += __shfl_xor(v, o, 64);
  if ((threadIdx.x & 63) == 0) red[threadIdx.x >> 6] = v;
  __syncthreads();
  v = red[0] + red[1] + red[2] + red[3];
  __syncthreads();
  return v;
}

// ------ O-chunk-partials reduce /l + residual + LayerNorm -> bf16 -----------
__global__ __launch_bounds__(256) void add_layernorm(
    const float* __restrict__ P, const float* __restrict__ l,
    const float* __restrict__ emb, const float* __restrict__ gamma,
    const float* __restrict__ beta, uint16_t* __restrict__ xB)
{
  __shared__ float red[4];
  int i = blockIdx.x, tid = threadIdx.x;
  float inv_l = 1.0f / l[i];
  int nc = (i >> 10) + 1;
  float s0 = 0.0f, s1 = 0.0f, s2 = 0.0f, s3 = 0.0f;
  for (int c = 0; c < nc; ++c) {
    float4 a = ((const float4*)(P + (size_t)c * 4194304 + (size_t)i * 1024))[tid];
    s0 += a.x; s1 += a.y; s2 += a.z; s3 += a.w;
  }
  float4 b = ((const float4*)(emb + (size_t)i * 1024))[tid];
  float x0 = s0 * inv_l + b.x, x1 = s1 * inv_l + b.y;
  float x2 = s2 * inv_l + b.z, x3 = s3 * inv_l + b.w;
  float mu = block_sum(x0 + x1 + x2 + x3, red) * (1.0f / 1024.0f);
  float d0 = x0 - mu, d1 = x1 - mu, d2 = x2 - mu, d3 = x3 - mu;
  float var = block_sum(d0 * d0 + d1 * d1 + d2 * d2 + d3 * d3, red) * (1.0f / 1024.0f);
  float rs = rsqrtf(var + 1e-5f);
  float4 g  = ((const float4*)gamma)[tid];
  float4 be = ((const float4*)beta)[tid];
  ushort4 o;
  o.x = f2bf(d0 * rs * g.x + be.x);
  o.y = f2bf(d1 * rs * g.y + be.y);
  o.z = f2bf(d2 * rs * g.z + be.z);
  o.w = f2bf(d3 * rs * g.w + be.w);
  ((ushort4*)(xB + (size_t)i * 1024))[tid] = o;
}

// ---------------- prep: all casts/transposes/bias/init in one launch --------
__global__ __launch_bounds__(256) void prep(
    const float* __restrict__ emb, const float* __restrict__ Wq,
    const float* __restrict__ Wk, const float* __restrict__ Wv,
    const float* __restrict__ W1, const float* __restrict__ W2,
    const float* __restrict__ bq, const float* __restrict__ bk,
    const float* __restrict__ bv, const float* __restrict__ b2,
    uint16_t* __restrict__ embB, uint16_t* __restrict__ WqkvT,
    uint16_t* __restrict__ W1T, uint16_t* __restrict__ W2T,
    float* __restrict__ bqkv, float* __restrict__ lvec,
    float* __restrict__ outInit)
{
  __shared__ float tile[32][33];
  int b = blockIdx.x, tid = threadIdx.x;
  if (b < 4096) {                        // emb cast
    int idx = b * 256 + tid;
    float4 v = ((const float4*)emb)[idx];
    ushort4 o; o.x = f2bf(v.x); o.y = f2bf(v.y); o.z = f2bf(v.z); o.w = f2bf(v.w);
    ((ushort4*)embB)[idx] = o;
    return;
  }
  int tx = tid & 31, ty = tid >> 5;
  if (b < 7168) {                        // Wq/Wk/Wv -> WqkvT
    int local = b - 4096;
    const float* in = (local < 1024) ? Wq : (local < 2048) ? Wk : Wv;
    uint16_t* o = WqkvT + (size_t)(local >> 10) * 1048576;
    int rem = local & 1023;
    int r0 = (rem >> 5) * 32, c0 = (rem & 31) * 32;
#pragma unroll
    for (int r = 0; r < 32; r += 8)
      tile[ty + r][tx] = in[(size_t)(r0 + ty + r) * 1024 + c0 + tx];
    __syncthreads();
#pragma unroll
    for (int r = 0; r < 32; r += 8)
      o[(size_t)(c0 + ty + r) * 1024 + r0 + tx] = f2bf(tile[tx][ty + r]);
    return;
  }
  if (b < 11264) {                       // W1 -> W1T
    int local = b - 7168;
    int c0 = (local & 127) * 32, r0 = (local >> 7) * 32;
#pragma unroll
    for (int r = 0; r < 32; r += 8)
      tile[ty + r][tx] = W1[(size_t)(r0 + ty + r) * 4096 + c0 + tx];
    __syncthreads();
#pragma unroll
    for (int r = 0; r < 32; r += 8)
      W1T[(size_t)(c0 + ty + r) * 1024 + r0 + tx] = f2bf(tile[tx][ty + r]);
    return;
  }
  if (b < 15360) {                       // W2 -> W2T
    int local = b - 11264;
    int c0 = (local & 31) * 32, r0 = (local >> 5) * 32;
#pragma unroll
    for (int r = 0; r < 32; r += 8)
      tile[ty + r][tx] = W2[(size_t)(r0 + ty + r) * 1024 + c0 + tx];
    __syncthreads();
#pragma unroll
    for (int r = 0; r < 32; r += 8)
      W2T[(size_t)(c0 + ty + r) * 4096 + r0 + tx] = f2bf(tile[tx][ty + r]);
    return;
  }
  if (b < 15372) {                       // pack bq|bk|bv
    int i = (b - 15360) * 256 + tid;
    bqkv[i] = (i < 1024) ? bq[i] : (i < 2048) ? bk[i - 1024] : bv[i - 2048];
    return;
  }
  if (b == 15372) {                      // lvec = 0
#pragma unroll
    for (int i = tid; i < 4096; i += 256) lvec[i] = 0.0f;
    return;
  }
  {                                      // d_out row init = b2
    int row = b - 15373;
    float4 bv4 = ((const float4*)b2)[tid];
    ((float4*)(outInit + (size_t)row * 1024))[tid] = bv4;
  }
}

// ---------------- launcher --------------------------------------------------
extern "C" void kernel_launch(void* const* d_in, const int* in_sizes, int n_in,
                              void* d_out, int out_size, void* d_ws, size_t ws_size,
                              hipStream_t stream) {
  const float* emb   = (const float*)d_in[0];
  const float* Wq    = (const float*)d_in[1];
  const float* bq    = (const float*)d_in[2];
  const float* Wk    = (const float*)d_in[3];
  const float* bk    = (const float*)d_in[4];
  const float* Wv    = (const float*)d_in[5];
  const float* bv    = (const float*)d_in[6];
  const float* gamma = (const float*)d_in[7];
  const float* beta  = (const float*)d_in[8];
  const float* W1    = (const float*)d_in[9];
  const float* b1    = (const float*)d_in[10];
  const float* W2    = (const float*)d_in[11];
  const float* b2    = (const float*)d_in[12];

  char* w = (char*)d_ws;
  const size_t MB = 1ull << 20;
  uint16_t* embB  = (uint16_t*)(w + 0 * MB);    // [4096,1024] bf16
  uint16_t* WqkvT = (uint16_t*)(w + 8 * MB);    // [3072,1024]
  uint16_t* W1T   = (uint16_t*)(w + 14 * MB);   // [4096,1024]
  uint16_t* W2T   = (uint16_t*)(w + 22 * MB);   // [1024,4096]
  float*    bqkv  = (float*)(w + 30 * MB);      // [3072]
  float*    lvec  = (float*)(w + 30 * MB + 65536); // [4096]
  uint16_t* QKVb  = (uint16_t*)(w + 31 * MB);   // [4096,3072] (V cols unused)
  uint16_t* Vt    = (uint16_t*)(w + 55 * MB);   // [1024,4096]
  uint16_t* Sb    = (uint16_t*)(w + 63 * MB);   // [4096,4096] bf16 exp(S)
  uint16_t* hB    = (uint16_t*)(w + 63 * MB);   // reuses Sb (dead after O)
  float*    Opart = (float*)(w + 95 * MB);      // [4][4096,1024] fp32 chunks
  uint16_t* xB    = (uint16_t*)(w + 0 * MB);    // reuses embB
  // total ws requirement: 159 MB

  prep<<<19469, 256, 0, stream>>>(emb, Wq, Wk, Wv, W1, W2, bq, bk, bv, b2,
                                  embB, WqkvT, W1T, W2T, bqkv, lvec,
                                  (float*)d_out);

  // fused QKV: Q,K -> QKVb; V -> Vt via operand-swapped MFMA
  gemm_qkv<<<768, 256, 0, stream>>>(embB, WqkvT, bqkv, QKVb, Vt);
  const uint16_t* Qb = QKVb;
  const uint16_t* Kb = QKVb + 1024;

  // exp(S): 64x128 causal tiles, XCD-swizzled 2048-slot launch
  gemm_s<<<2048, 256, 0, stream>>>(Qb, Kb, Sb, lvec, 3072, 3072, 4096, 0.03125f);

  // O' = exp(S) @ V: 128x128 triangular K-chunks, XCD-swizzled, 640 blocks
  gemm_o<<<640, 256, 0, stream>>>(Sb, Vt, Opart);

  // reduce O chunk-partials, /l, + residual, LayerNorm -> xB
  add_layernorm<<<4096, 256, 0, stream>>>(Opart, lvec, emb, gamma, beta, xB);

  // FFN1 (XCD-swizzled 1-D grid)
  gemm_ffn1<<<1024, 256, 0, stream>>>(xB, W1T, b1, hB);

  // FFN2: 128x128 split-K=4, XCD-swizzled, atomicAdd into b2-init'd d_out
  gemm_ffn2<<<1024, 256, 0, stream>>>(hB, W2T, (float*)d_out);
}

// Round 10
// 337.017 us; speedup vs baseline: 1.0871x; 1.0871x over previous
//
#include <hip/hip_runtime.h>
#include <stdint.h>

// Round 10: revert FFN2 to the round-8 n64/split-K=2/atomic form (round 9's
// split-K=4 doubled atomics 8M->16M and was atomic-RMW-bound: +22.7us at
// ~2.8ns/atomic). gemm_o re-ordered long-blocks-first (short 2-6 iter blocks
// launch last -> smaller tail). gemm_s keeps XCD launch. BK=64, XOR LDS
// swizzle, shift-free softmax, operand-swapped-V QKV. ws: 159 MB.

using short8 = __attribute__((ext_vector_type(8))) short;
using f32x4  = __attribute__((ext_vector_type(4))) float;

__device__ __forceinline__ uint16_t f2bf(float f) {
  uint32_t u = __builtin_bit_cast(uint32_t, f);
  u += 0x7FFFu + ((u >> 16) & 1u);        // RNE, inputs are finite
  return (uint16_t)(u >> 16);
}

__device__ __forceinline__ void gload_lds16(const uint16_t* g, uint16_t* l) {
  __builtin_amdgcn_global_load_lds(
      (__attribute__((address_space(1))) void*)(void*)g,
      (__attribute__((address_space(3))) void*)l, 16, 0, 0);
}

// LDS swizzle (BK=64): 16B slot s holds global chunk-col (s&7)^((s>>3)&7) of
// row s>>3. Read (row r, chunk cc) -> slot r*8 + (cc ^ (r&7)).

// ---------------- QKV gemm: 128x128, 1-D grid 768 (id%8==bm%8) --------------
__global__ __launch_bounds__(256) void gemm_qkv(
    const uint16_t* __restrict__ A, const uint16_t* __restrict__ Bt,
    const float* __restrict__ bias, uint16_t* __restrict__ Cout,
    uint16_t* __restrict__ Vt)
{
  constexpr int BK = 64;
  __shared__ uint16_t As[128 * BK];
  __shared__ uint16_t Bs[128 * BK];
  int id = blockIdx.x;
  int bm = id & 31, bn = id >> 5;
  bool vblk = (bn >= 16);

  int tid  = threadIdx.x;
  int lane = tid & 63;
  int wave = tid >> 6;
  int wm = (wave >> 1) * 64, wn = (wave & 1) * 64;
  int lr = lane & 15, quad = lane >> 4;

  const uint16_t *Ag[4], *Bg[4];
  uint16_t *Al[4], *Bl[4];
#pragma unroll
  for (int s = 0; s < 4; ++s) {
    int c = tid + 256 * s;
    int r = c >> 3, q = (c & 7) ^ (r & 7);
    Ag[s] = A  + (size_t)(bm * 128 + r) * 1024 + q * 8;
    Bg[s] = Bt + (size_t)(bn * 128 + r) * 1024 + q * 8;
    Al[s] = As + c * 8;
    Bl[s] = Bs + c * 8;
  }
  const uint16_t* Fa = vblk ? Bs : As;
  const uint16_t* Fb = vblk ? As : Bs;

  f32x4 acc[4][4] = {};

  for (int k0 = 0; k0 < 1024; k0 += BK) {
    __syncthreads();
#pragma unroll
    for (int s = 0; s < 4; ++s) gload_lds16(Ag[s] + k0, Al[s]);
#pragma unroll
    for (int s = 0; s < 4; ++s) gload_lds16(Bg[s] + k0, Bl[s]);
    __syncthreads();
#pragma unroll
    for (int h = 0; h < 2; ++h) {
      short8 af[4], bfr[4];
      int cc = quad + 4 * h;
#pragma unroll
      for (int i = 0; i < 4; ++i) {
        int r = wm + i * 16 + lr;
        af[i] = *(const short8*)(&Fa[(r * 8 + (cc ^ (r & 7))) * 8]);
      }
#pragma unroll
      for (int j = 0; j < 4; ++j) {
        int r = wn + j * 16 + lr;
        bfr[j] = *(const short8*)(&Fb[(r * 8 + (cc ^ (r & 7))) * 8]);
      }
#pragma unroll
      for (int i = 0; i < 4; ++i)
#pragma unroll
        for (int j = 0; j < 4; ++j)
          acc[i][j] = __builtin_amdgcn_mfma_f32_16x16x32_bf16(af[i], bfr[j], acc[i][j], 0, 0, 0);
    }
  }

  if (vblk) {
#pragma unroll
    for (int i = 0; i < 4; ++i) {
#pragma unroll
      for (int r = 0; r < 4; ++r) {
        int n = bn * 128 + wm + i * 16 + quad * 4 + r;
        float bv = bias[n];
        uint16_t* dst = Vt + (size_t)(n - 2048) * 4096 + bm * 128;
#pragma unroll
        for (int j = 0; j < 4; ++j)
          dst[wn + j * 16 + lr] = f2bf(acc[i][j][r] + bv);
      }
    }
  } else {
    int row0 = bm * 128 + wm + quad * 4;
    int col0 = bn * 128 + wn + lr;
#pragma unroll
    for (int j = 0; j < 4; ++j) {
      int col = col0 + j * 16;
      float bv = bias[col];
#pragma unroll
      for (int i = 0; i < 4; ++i)
#pragma unroll
        for (int r = 0; r < 4; ++r)
          Cout[(size_t)(row0 + i * 16 + r) * 3072 + col] = f2bf(acc[i][j][r] + bv);
    }
  }
}

// ---------------- FFN1 gemm: 128x128, 1-D grid 1024 (id%8==bm%8) ------------
__global__ __launch_bounds__(256) void gemm_ffn1(
    const uint16_t* __restrict__ A, const uint16_t* __restrict__ Bt,
    const float* __restrict__ bias, uint16_t* __restrict__ Cout)
{
  constexpr int BK = 64;
  __shared__ uint16_t As[128 * BK];
  __shared__ uint16_t Bs[128 * BK];
  int id = blockIdx.x;
  int bm = id & 31, bn = id >> 5;

  int tid  = threadIdx.x;
  int lane = tid & 63;
  int wave = tid >> 6;
  int wm = (wave >> 1) * 64, wn = (wave & 1) * 64;
  int lr = lane & 15, quad = lane >> 4;

  const uint16_t *Ag[4], *Bg[4];
  uint16_t *Al[4], *Bl[4];
#pragma unroll
  for (int s = 0; s < 4; ++s) {
    int c = tid + 256 * s;
    int r = c >> 3, q = (c & 7) ^ (r & 7);
    Ag[s] = A  + (size_t)(bm * 128 + r) * 1024 + q * 8;
    Bg[s] = Bt + (size_t)(bn * 128 + r) * 1024 + q * 8;
    Al[s] = As + c * 8;
    Bl[s] = Bs + c * 8;
  }

  f32x4 acc[4][4] = {};

  for (int k0 = 0; k0 < 1024; k0 += BK) {
    __syncthreads();
#pragma unroll
    for (int s = 0; s < 4; ++s) gload_lds16(Ag[s] + k0, Al[s]);
#pragma unroll
    for (int s = 0; s < 4; ++s) gload_lds16(Bg[s] + k0, Bl[s]);
    __syncthreads();
#pragma unroll
    for (int h = 0; h < 2; ++h) {
      short8 af[4], bfr[4];
      int cc = quad + 4 * h;
#pragma unroll
      for (int i = 0; i < 4; ++i) {
        int r = wm + i * 16 + lr;
        af[i] = *(const short8*)(&As[(r * 8 + (cc ^ (r & 7))) * 8]);
      }
#pragma unroll
      for (int j = 0; j < 4; ++j) {
        int r = wn + j * 16 + lr;
        bfr[j] = *(const short8*)(&Bs[(r * 8 + (cc ^ (r & 7))) * 8]);
      }
#pragma unroll
      for (int i = 0; i < 4; ++i)
#pragma unroll
        for (int j = 0; j < 4; ++j)
          acc[i][j] = __builtin_amdgcn_mfma_f32_16x16x32_bf16(af[i], bfr[j], acc[i][j], 0, 0, 0);
    }
  }

  int row0 = bm * 128 + wm + quad * 4;
  int col0 = bn * 128 + wn + lr;
#pragma unroll
  for (int j = 0; j < 4; ++j) {
    int col = col0 + j * 16;
    float bv = bias[col];
#pragma unroll
    for (int i = 0; i < 4; ++i)
#pragma unroll
      for (int r = 0; r < 4; ++r)
        Cout[(size_t)(row0 + i * 16 + r) * 4096 + col] =
            f2bf(fmaxf(acc[i][j][r] + bv, 0.0f));
  }
}

// ---------------- causal S-gemm, 64x128 tiles, XCD-swizzled -----------------
// 1-D grid 2048: i64 = id&63 (Q-tile sharers co-XCD), bn = id>>6;
// early-exit if bn > i64>>1. Fused row-sum atomics into lvec.
__global__ __launch_bounds__(256) void gemm_s(
    const uint16_t* __restrict__ Qm, const uint16_t* __restrict__ Km,
    uint16_t* __restrict__ Sb, float* __restrict__ lvec,
    int lda, int ldb, int ldc, float scale)
{
  constexpr int BK = 64;
  __shared__ uint16_t As[64 * BK];
  __shared__ uint16_t Bs[128 * BK];
  int id = blockIdx.x;
  int i64 = id & 63, bn = id >> 6;
  if (bn > (i64 >> 1)) return;

  int tid  = threadIdx.x;
  int lane = tid & 63;
  int wave = tid >> 6;
  int wm = (wave >> 1) * 32, wn = (wave & 1) * 64;
  int lr = lane & 15, quad = lane >> 4;

  const uint16_t *Ag[2], *Bg[4];
  uint16_t *Al[2], *Bl[4];
#pragma unroll
  for (int s = 0; s < 2; ++s) {
    int c = tid + 256 * s;
    int r = c >> 3, q = (c & 7) ^ (r & 7);
    Ag[s] = Qm + (size_t)(i64 * 64 + r) * lda + q * 8;
    Al[s] = As + c * 8;
  }
#pragma unroll
  for (int s = 0; s < 4; ++s) {
    int c = tid + 256 * s;
    int r = c >> 3, q = (c & 7) ^ (r & 7);
    Bg[s] = Km + (size_t)(bn * 128 + r) * ldb + q * 8;
    Bl[s] = Bs + c * 8;
  }

  f32x4 acc[2][4] = {};

  for (int k0 = 0; k0 < 1024; k0 += BK) {
    __syncthreads();
#pragma unroll
    for (int s = 0; s < 2; ++s) gload_lds16(Ag[s] + k0, Al[s]);
#pragma unroll
    for (int s = 0; s < 4; ++s) gload_lds16(Bg[s] + k0, Bl[s]);
    __syncthreads();
#pragma unroll
    for (int h = 0; h < 2; ++h) {
      short8 af[2], bfr[4];
      int cc = quad + 4 * h;
#pragma unroll
      for (int i = 0; i < 2; ++i) {
        int r = wm + i * 16 + lr;
        af[i] = *(const short8*)(&As[(r * 8 + (cc ^ (r & 7))) * 8]);
      }
#pragma unroll
      for (int j = 0; j < 4; ++j) {
        int r = wn + j * 16 + lr;
        bfr[j] = *(const short8*)(&Bs[(r * 8 + (cc ^ (r & 7))) * 8]);
      }
#pragma unroll
      for (int i = 0; i < 2; ++i)
#pragma unroll
        for (int j = 0; j < 4; ++j)
          acc[i][j] = __builtin_amdgcn_mfma_f32_16x16x32_bf16(af[i], bfr[j], acc[i][j], 0, 0, 0);
    }
  }

  int row0 = i64 * 64 + wm + quad * 4;
  int col0 = bn * 128 + wn + lr;
#pragma unroll
  for (int i = 0; i < 2; ++i) {
#pragma unroll
    for (int r = 0; r < 4; ++r) {
      int row = row0 + i * 16 + r;
      float s = 0.0f;
#pragma unroll
      for (int j = 0; j < 4; ++j) {
        int col = col0 + j * 16;
        float v = (col <= row) ? __expf(acc[i][j][r] * scale) : 0.0f;
        Sb[(size_t)row * ldc + col] = f2bf(v);
        s += v;
      }
#pragma unroll
      for (int o = 8; o > 0; o >>= 1) s += __shfl_xor(s, o, 64);
      if (lr == 0) unsafeAtomicAdd(&lvec[row], s);
    }
  }
}

// ---------------- O-gemm: 128x128, triangular K-chunks, XCD-swizzled --------
// 1-D grid 640: id = bn*80 + p (id%8==p%8 co-XCD). p ordered LONG-FIRST:
// p<25: c=0,bm=7+p (16 it); p<49: c=1,bm=8+(p-25); p<65: c=2,bm=16+(p-49);
// p<73: c=3,bm=24+(p-65); else c=0,bm=79-p (short 2..14-iter blocks last).
__global__ __launch_bounds__(256) void gemm_o(
    const uint16_t* __restrict__ Sb, const uint16_t* __restrict__ Vt,
    float* __restrict__ Opart)
{
  constexpr int BK = 64;
  __shared__ uint16_t As[128 * BK];
  __shared__ uint16_t Bs[128 * BK];
  int id = blockIdx.x;
  int bn = id / 80, p = id % 80;
  int c, bm;
  if      (p < 25) { c = 0; bm = 7 + p; }
  else if (p < 49) { c = 1; bm = 8 + (p - 25); }
  else if (p < 65) { c = 2; bm = 16 + (p - 49); }
  else if (p < 73) { c = 3; bm = 24 + (p - 65); }
  else             { c = 0; bm = 79 - p; }
  int klo = c << 10;
  int khi = (bm + 1) << 7; if (khi > ((c + 1) << 10)) khi = (c + 1) << 10;

  int tid  = threadIdx.x;
  int lane = tid & 63;
  int wave = tid >> 6;
  int wm = (wave >> 1) * 64, wn = (wave & 1) * 64;
  int lr = lane & 15, quad = lane >> 4;

  const uint16_t *Ag[4], *Bg[4];
  uint16_t *Al[4], *Bl[4];
#pragma unroll
  for (int s = 0; s < 4; ++s) {
    int cch = tid + 256 * s;
    int r = cch >> 3, q = (cch & 7) ^ (r & 7);
    Ag[s] = Sb + (size_t)(bm * 128 + r) * 4096 + q * 8;
    Bg[s] = Vt + (size_t)(bn * 128 + r) * 4096 + q * 8;
    Al[s] = As + cch * 8;
    Bl[s] = Bs + cch * 8;
  }

  f32x4 acc[4][4] = {};

  for (int k0 = klo; k0 < khi; k0 += BK) {
    __syncthreads();
#pragma unroll
    for (int s = 0; s < 4; ++s) gload_lds16(Ag[s] + k0, Al[s]);
#pragma unroll
    for (int s = 0; s < 4; ++s) gload_lds16(Bg[s] + k0, Bl[s]);
    __syncthreads();
#pragma unroll
    for (int h = 0; h < 2; ++h) {
      short8 af[4], bfr[4];
      int cc = quad + 4 * h;
#pragma unroll
      for (int i = 0; i < 4; ++i) {
        int r = wm + i * 16 + lr;
        af[i] = *(const short8*)(&As[(r * 8 + (cc ^ (r & 7))) * 8]);
      }
#pragma unroll
      for (int j = 0; j < 4; ++j) {
        int r = wn + j * 16 + lr;
        bfr[j] = *(const short8*)(&Bs[(r * 8 + (cc ^ (r & 7))) * 8]);
      }
#pragma unroll
      for (int i = 0; i < 4; ++i)
#pragma unroll
        for (int j = 0; j < 4; ++j)
          acc[i][j] = __builtin_amdgcn_mfma_f32_16x16x32_bf16(af[i], bfr[j], acc[i][j], 0, 0, 0);
    }
  }

  float* P = Opart + (size_t)c * 4194304;
  int row0 = bm * 128 + wm + quad * 4;
  int col0 = bn * 128 + wn + lr;
#pragma unroll
  for (int j = 0; j < 4; ++j)
#pragma unroll
    for (int i = 0; i < 4; ++i)
#pragma unroll
      for (int r = 0; r < 4; ++r)
        P[(size_t)(row0 + i * 16 + r) * 1024 + col0 + j * 16] = acc[i][j][r];
}

// ---------------- FFN2: 128x64, split-K=2, atomic epilogue, XCD-swizzled ----
// (round-8 form, measured 63us) 1-D grid 1024: id = bn*64 + p (id%8==p%8).
// bm = p>>1, half = p&1. unsafeAtomicAdd into b2-pre-initialized d_out.
__global__ __launch_bounds__(256) void gemm_ffn2(
    const uint16_t* __restrict__ A, const uint16_t* __restrict__ Bt,
    float* __restrict__ Cout)
{
  constexpr int BK = 64;
  __shared__ uint16_t As[128 * BK];
  __shared__ uint16_t Bs[64 * BK];
  int id = blockIdx.x;
  int bn = id >> 6, p = id & 63;
  int bm = p >> 1, half = p & 1;
  int klo = half ? 2048 : 0, khi = half ? 4096 : 2048;

  int tid  = threadIdx.x;
  int lane = tid & 63;
  int wave = tid >> 6;
  int wm = (wave & 1) * 64, wn = (wave >> 1) * 32;
  int lr = lane & 15, quad = lane >> 4;

  const uint16_t *Ag[4], *Bg[2];
  uint16_t *Al[4], *Bl[2];
#pragma unroll
  for (int s = 0; s < 4; ++s) {
    int c = tid + 256 * s;
    int r = c >> 3, q = (c & 7) ^ (r & 7);
    Ag[s] = A + (size_t)(bm * 128 + r) * 4096 + q * 8;
    Al[s] = As + c * 8;
  }
#pragma unroll
  for (int s = 0; s < 2; ++s) {
    int c = tid + 256 * s;
    int r = c >> 3, q = (c & 7) ^ (r & 7);
    Bg[s] = Bt + (size_t)(bn * 64 + r) * 4096 + q * 8;
    Bl[s] = Bs + c * 8;
  }

  f32x4 acc[4][2] = {};

  for (int k0 = klo; k0 < khi; k0 += BK) {
    __syncthreads();
#pragma unroll
    for (int s = 0; s < 4; ++s) gload_lds16(Ag[s] + k0, Al[s]);
#pragma unroll
    for (int s = 0; s < 2; ++s) gload_lds16(Bg[s] + k0, Bl[s]);
    __syncthreads();
#pragma unroll
    for (int h = 0; h < 2; ++h) {
      short8 af[4], bfr[2];
      int cc = quad + 4 * h;
#pragma unroll
      for (int i = 0; i < 4; ++i) {
        int r = wm + i * 16 + lr;
        af[i] = *(const short8*)(&As[(r * 8 + (cc ^ (r & 7))) * 8]);
      }
#pragma unroll
      for (int j = 0; j < 2; ++j) {
        int r = wn + j * 16 + lr;
        bfr[j] = *(const short8*)(&Bs[(r * 8 + (cc ^ (r & 7))) * 8]);
      }
#pragma unroll
      for (int i = 0; i < 4; ++i)
#pragma unroll
        for (int j = 0; j < 2; ++j)
          acc[i][j] = __builtin_amdgcn_mfma_f32_16x16x32_bf16(af[i], bfr[j], acc[i][j], 0, 0, 0);
    }
  }

  int row0 = bm * 128 + wm + quad * 4;
  int col0 = bn * 64 + wn + lr;
#pragma unroll
  for (int j = 0; j < 2; ++j)
#pragma unroll
    for (int i = 0; i < 4; ++i)
#pragma unroll
      for (int r = 0; r < 4; ++r) {
        size_t idx = (size_t)(row0 + i * 16 + r) * 1024 + col0 + j * 16;
        unsafeAtomicAdd(&Cout[idx], acc[i][j][r]);
      }
}

// ---------------- reductions ------------------------------------------------
__device__ __forceinline__ float block_sum(float v, float* red) {
#pragma unroll
  for (int o = 32; o > 0; o >>= 1) v += __shfl_xor(v, o, 64);
  if ((threadIdx.x & 63) == 0) red[threadIdx.x >> 6] = v;
  __syncthreads();
  v = red[0] + red[1] + red[2] + red[3];
  __syncthreads();
  return v;
}

// ------ O-chunk-partials reduce /l + residual + LayerNorm -> bf16 -----------
__global__ __launch_bounds__(256) void add_layernorm(
    const float* __restrict__ P, const float* __restrict__ l,
    const float* __restrict__ emb, const float* __restrict__ gamma,
    const float* __restrict__ beta, uint16_t* __restrict__ xB)
{
  __shared__ float red[4];
  int i = blockIdx.x, tid = threadIdx.x;
  float inv_l = 1.0f / l[i];
  int nc = (i >> 10) + 1;
  float s0 = 0.0f, s1 = 0.0f, s2 = 0.0f, s3 = 0.0f;
  for (int c = 0; c < nc; ++c) {
    float4 a = ((const float4*)(P + (size_t)c * 4194304 + (size_t)i * 1024))[tid];
    s0 += a.x; s1 += a.y; s2 += a.z; s3 += a.w;
  }
  float4 b = ((const float4*)(emb + (size_t)i * 1024))[tid];
  float x0 = s0 * inv_l + b.x, x1 = s1 * inv_l + b.y;
  float x2 = s2 * inv_l + b.z, x3 = s3 * inv_l + b.w;
  float mu = block_sum(x0 + x1 + x2 + x3, red) * (1.0f / 1024.0f);
  float d0 = x0 - mu, d1 = x1 - mu, d2 = x2 - mu, d3 = x3 - mu;
  float var = block_sum(d0 * d0 + d1 * d1 + d2 * d2 + d3 * d3, red) * (1.0f / 1024.0f);
  float rs = rsqrtf(var + 1e-5f);
  float4 g  = ((const float4*)gamma)[tid];
  float4 be = ((const float4*)beta)[tid];
  ushort4 o;
  o.x = f2bf(d0 * rs * g.x + be.x);
  o.y = f2bf(d1 * rs * g.y + be.y);
  o.z = f2bf(d2 * rs * g.z + be.z);
  o.w = f2bf(d3 * rs * g.w + be.w);
  ((ushort4*)(xB + (size_t)i * 1024))[tid] = o;
}

// ---------------- prep: all casts/transposes/bias/init in one launch --------
__global__ __launch_bounds__(256) void prep(
    const float* __restrict__ emb, const float* __restrict__ Wq,
    const float* __restrict__ Wk, const float* __restrict__ Wv,
    const float* __restrict__ W1, const float* __restrict__ W2,
    const float* __restrict__ bq, const float* __restrict__ bk,
    const float* __restrict__ bv, const float* __restrict__ b2,
    uint16_t* __restrict__ embB, uint16_t* __restrict__ WqkvT,
    uint16_t* __restrict__ W1T, uint16_t* __restrict__ W2T,
    float* __restrict__ bqkv, float* __restrict__ lvec,
    float* __restrict__ outInit)
{
  __shared__ float tile[32][33];
  int b = blockIdx.x, tid = threadIdx.x;
  if (b < 4096) {                        // emb cast
    int idx = b * 256 + tid;
    float4 v = ((const float4*)emb)[idx];
    ushort4 o; o.x = f2bf(v.x); o.y = f2bf(v.y); o.z = f2bf(v.z); o.w = f2bf(v.w);
    ((ushort4*)embB)[idx] = o;
    return;
  }
  int tx = tid & 31, ty = tid >> 5;
  if (b < 7168) {                        // Wq/Wk/Wv -> WqkvT
    int local = b - 4096;
    const float* in = (local < 1024) ? Wq : (local < 2048) ? Wk : Wv;
    uint16_t* o = WqkvT + (size_t)(local >> 10) * 1048576;
    int rem = local & 1023;
    int r0 = (rem >> 5) * 32, c0 = (rem & 31) * 32;
#pragma unroll
    for (int r = 0; r < 32; r += 8)
      tile[ty + r][tx] = in[(size_t)(r0 + ty + r) * 1024 + c0 + tx];
    __syncthreads();
#pragma unroll
    for (int r = 0; r < 32; r += 8)
      o[(size_t)(c0 + ty + r) * 1024 + r0 + tx] = f2bf(tile[tx][ty + r]);
    return;
  }
  if (b < 11264) {                       // W1 -> W1T
    int local = b - 7168;
    int c0 = (local & 127) * 32, r0 = (local >> 7) * 32;
#pragma unroll
    for (int r = 0; r < 32; r += 8)
      tile[ty + r][tx] = W1[(size_t)(r0 + ty + r) * 4096 + c0 + tx];
    __syncthreads();
#pragma unroll
    for (int r = 0; r < 32; r += 8)
      W1T[(size_t)(c0 + ty + r) * 1024 + r0 + tx] = f2bf(tile[tx][ty + r]);
    return;
  }
  if (b < 15360) {                       // W2 -> W2T
    int local = b - 11264;
    int c0 = (local & 31) * 32, r0 = (local >> 5) * 32;
#pragma unroll
    for (int r = 0; r < 32; r += 8)
      tile[ty + r][tx] = W2[(size_t)(r0 + ty + r) * 1024 + c0 + tx];
    __syncthreads();
#pragma unroll
    for (int r = 0; r < 32; r += 8)
      W2T[(size_t)(c0 + ty + r) * 4096 + r0 + tx] = f2bf(tile[tx][ty + r]);
    return;
  }
  if (b < 15372) {                       // pack bq|bk|bv
    int i = (b - 15360) * 256 + tid;
    bqkv[i] = (i < 1024) ? bq[i] : (i < 2048) ? bk[i - 1024] : bv[i - 2048];
    return;
  }
  if (b == 15372) {                      // lvec = 0
#pragma unroll
    for (int i = tid; i < 4096; i += 256) lvec[i] = 0.0f;
    return;
  }
  {                                      // d_out row init = b2
    int row = b - 15373;
    float4 bv4 = ((const float4*)b2)[tid];
    ((float4*)(outInit + (size_t)row * 1024))[tid] = bv4;
  }
}

// ---------------- launcher --------------------------------------------------
extern "C" void kernel_launch(void* const* d_in, const int* in_sizes, int n_in,
                              void* d_out, int out_size, void* d_ws, size_t ws_size,
                              hipStream_t stream) {
  const float* emb   = (const float*)d_in[0];
  const float* Wq    = (const float*)d_in[1];
  const float* bq    = (const float*)d_in[2];
  const float* Wk    = (const float*)d_in[3];
  const float* bk    = (const float*)d_in[4];
  const float* Wv    = (const float*)d_in[5];
  const float* bv    = (const float*)d_in[6];
  const float* gamma = (const float*)d_in[7];
  const float* beta  = (const float*)d_in[8];
  const float* W1    = (const float*)d_in[9];
  const float* b1    = (const float*)d_in[10];
  const float* W2    = (const float*)d_in[11];
  const float* b2    = (const float*)d_in[12];

  char* w = (char*)d_ws;
  const size_t MB = 1ull << 20;
  uint16_t* embB  = (uint16_t*)(w + 0 * MB);    // [4096,1024] bf16
  uint16_t* WqkvT = (uint16_t*)(w + 8 * MB);    // [3072,1024]
  uint16_t* W1T   = (uint16_t*)(w + 14 * MB);   // [4096,1024]
  uint16_t* W2T   = (uint16_t*)(w + 22 * MB);   // [1024,4096]
  float*    bqkv  = (float*)(w + 30 * MB);      // [3072]
  float*    lvec  = (float*)(w + 30 * MB + 65536); // [4096]
  uint16_t* QKVb  = (uint16_t*)(w + 31 * MB);   // [4096,3072] (V cols unused)
  uint16_t* Vt    = (uint16_t*)(w + 55 * MB);   // [1024,4096]
  uint16_t* Sb    = (uint16_t*)(w + 63 * MB);   // [4096,4096] bf16 exp(S)
  uint16_t* hB    = (uint16_t*)(w + 63 * MB);   // reuses Sb (dead after O)
  float*    Opart = (float*)(w + 95 * MB);      // [4][4096,1024] fp32 chunks
  uint16_t* xB    = (uint16_t*)(w + 0 * MB);    // reuses embB
  // total ws requirement: 159 MB

  prep<<<19469, 256, 0, stream>>>(emb, Wq, Wk, Wv, W1, W2, bq, bk, bv, b2,
                                  embB, WqkvT, W1T, W2T, bqkv, lvec,
                                  (float*)d_out);

  // fused QKV: Q,K -> QKVb; V -> Vt via operand-swapped MFMA
  gemm_qkv<<<768, 256, 0, stream>>>(embB, WqkvT, bqkv, QKVb, Vt);
  const uint16_t* Qb = QKVb;
  const uint16_t* Kb = QKVb + 1024;

  // exp(S): 64x128 causal tiles, XCD-swizzled 2048-slot launch
  gemm_s<<<2048, 256, 0, stream>>>(Qb, Kb, Sb, lvec, 3072, 3072, 4096, 0.03125f);

  // O' = exp(S) @ V: 128x128 triangular K-chunks, XCD-swizzled, long-first
  gemm_o<<<640, 256, 0, stream>>>(Sb, Vt, Opart);

  // reduce O chunk-partials, /l, + residual, LayerNorm -> xB
  add_layernorm<<<4096, 256, 0, stream>>>(Opart, lvec, emb, gamma, beta, xB);

  // FFN1 (XCD-swizzled 1-D grid)
  gemm_ffn1<<<1024, 256, 0, stream>>>(xB, W1T, b1, hB);

  // FFN2: round-8 n64 split-K=2 atomic form (measured 63us)
  gemm_ffn2<<<1024, 256, 0, stream>>>(hB, W2T, (float*)d_out);
}